// Round 5
// baseline (526.455 us; speedup 1.0000x reference)
//
#include <hip/hip_runtime.h>

#define N_NODES 100000
#define N_EDGES 1600000
#define CH 128
#define OUTC 40
#define CAP 64        // max in-degree; Poisson(16) => P(>=64) ~ 1e-20
#define NBKT 98       // buckets by dst>>10 (1024 nodes each)
#define BKT_CAP 18432 // mean 16384, sigma ~127 -> 16-sigma headroom
#define P1_EDGES 4096 // edges binned per block
#define ROW4 16       // uint4 per feature row: 128 bf16 = 256 B = 16 * 16 B

typedef __attribute__((ext_vector_type(8))) short bf16x8s;
typedef __attribute__((ext_vector_type(4))) float f32x4;

__device__ __forceinline__ unsigned short f2b_rne(float f) {
    union { float f; unsigned int u; } c; c.f = f;
    unsigned int r = (c.u + 0x7FFF + ((c.u >> 16) & 1)) >> 16;
    return (unsigned short)r;
}
__device__ __forceinline__ float b2f(unsigned short b) {
    union { float f; unsigned int u; } c; c.u = ((unsigned int)b) << 16;
    return c.f;
}
__device__ __forceinline__ void acc2(float& a0, float& a1, unsigned int v) {
    a0 += b2f((unsigned short)(v & 0xFFFF));
    a1 += b2f((unsigned short)(v >> 16));
}

// ---------------- fp32 -> bf16 convert ----------------
__global__ __launch_bounds__(256) void conv_f32_bf16(const float4* __restrict__ in,
                                                     ushort4* __restrict__ out, int n8) {
    int i = blockIdx.x * 256 + threadIdx.x;
    if (i >= n8) return;
    float4 a = in[i * 2], b = in[i * 2 + 1];
    ushort4 o0, o1;
    o0.x = f2b_rne(a.x); o0.y = f2b_rne(a.y); o0.z = f2b_rne(a.z); o0.w = f2b_rne(a.w);
    o1.x = f2b_rne(b.x); o1.y = f2b_rne(b.y); o1.z = f2b_rne(b.z); o1.w = f2b_rne(b.w);
    out[i * 2] = o0; out[i * 2 + 1] = o1;
}

__global__ __launch_bounds__(256) void zero_ints(int* __restrict__ p, int n) {
    int i = blockIdx.x * 256 + threadIdx.x;
    if (i < n) p[i] = 0;
}

// ---------------- P1: bin edges by destination bucket (coalesced writes) ----------------
__global__ __launch_bounds__(256) void bin_edges(const int* __restrict__ esrc,
                                                 const int* __restrict__ edst,
                                                 int* __restrict__ gcursor,
                                                 uint2* __restrict__ bins) {
    __shared__ uint2 stage[P1_EDGES];      // 32 KB
    __shared__ int lcnt[NBKT];
    __shared__ int lofs[NBKT];             // inclusive scan
    __shared__ int lpos[NBKT];             // running placement cursor
    __shared__ int gbase[NBKT];
    const int tid = threadIdx.x;
    const int e0 = blockIdx.x * P1_EDGES;

    for (int i = tid; i < NBKT; i += 256) lcnt[i] = 0;
    __syncthreads();

    int s[16], d[16];
#pragma unroll
    for (int i = 0; i < 16; ++i) {
        int e = e0 + i * 256 + tid;
        if (e < N_EDGES) { s[i] = esrc[e]; d[i] = edst[e]; }
        else d[i] = -1;
    }
#pragma unroll
    for (int i = 0; i < 16; ++i)
        if (d[i] >= 0) atomicAdd(&lcnt[d[i] >> 10], 1);
    __syncthreads();

    // Kogge-Stone inclusive scan over NBKT entries
    if (tid < NBKT) lofs[tid] = lcnt[tid];
    __syncthreads();
    for (int dd = 1; dd < NBKT; dd <<= 1) {
        int v = 0;
        if (tid < NBKT && tid >= dd) v = lofs[tid - dd];
        __syncthreads();
        if (tid < NBKT) lofs[tid] += v;
        __syncthreads();
    }
    if (tid < NBKT) {
        lpos[tid] = lofs[tid] - lcnt[tid];                 // exclusive base
        gbase[tid] = atomicAdd(&gcursor[tid], lcnt[tid]);  // claim global range
    }
    __syncthreads();

    // place records into LDS, grouped by bucket
#pragma unroll
    for (int i = 0; i < 16; ++i) {
        if (d[i] >= 0) {
            int b = d[i] >> 10;
            int slot = atomicAdd(&lpos[b], 1);
            stage[slot] = make_uint2((unsigned)s[i], (unsigned)d[i]);
        }
    }
    __syncthreads();

    // coalesced copy-out: consecutive r in a bucket -> consecutive global slots
    int total = lofs[NBKT - 1];
    for (int r = tid; r < total; r += 256) {
        uint2 rec = stage[r];
        int b = (int)(rec.y >> 10);
        int excl = lofs[b] - lcnt[b];
        int pos = gbase[b] + (r - excl);
        if (pos < BKT_CAP) bins[(size_t)b * BKT_CAP + pos] = rec;
    }
}

// ---------------- P2: build adj from bins (one block per bucket; single-XCD writes) ----------
__global__ __launch_bounds__(256) void build_from_bins(const uint2* __restrict__ bins,
                                                       const int* __restrict__ gcursor,
                                                       int* __restrict__ adj,
                                                       int* __restrict__ cnt) {
    __shared__ int lc[1024];
    const int b = blockIdx.x;
    const int tid = threadIdx.x;
    const int base = b << 10;
    for (int i = tid; i < 1024; i += 256) lc[i] = 0;
    __syncthreads();
    int n = gcursor[b]; if (n > BKT_CAP) n = BKT_CAP;
    const uint2* myb = bins + (size_t)b * BKT_CAP;
    for (int i = tid; i < n; i += 256) {
        uint2 r = myb[i];
        int local = (int)r.y - base;
        int slot = atomicAdd(&lc[local], 1);
        if (slot < CAP) adj[((int)r.y << 6) + slot] = (int)r.x;
    }
    __syncthreads();
    for (int i = tid; i < 1024; i += 256) {
        int node = base + i;
        if (node < N_NODES) cnt[node] = lc[i];
    }
}

// ---------------- pack weights into MFMA B-frag order ----------------
__global__ __launch_bounds__(256) void pack_w3(const float* __restrict__ W0,
                                               const float* __restrict__ W1,
                                               const float* __restrict__ W2,
                                               unsigned short* __restrict__ P0,
                                               unsigned short* __restrict__ P1,
                                               unsigned short* __restrict__ P2) {
    int t = blockIdx.x * 256 + threadIdx.x;
    if (t >= 3 * 2048) return;
    int which = t >> 11;
    int rem = t & 2047;
    int lane = rem & 63;
    int ks = (rem >> 6) & 3;
    int nt = rem >> 8;
    const float* W = which == 0 ? W0 : (which == 1 ? W1 : W2);
    unsigned short* P = which == 0 ? P0 : (which == 1 ? P1 : P2);
    int n = nt * 16 + (lane & 15);
    int kbase = ks * 32 + (lane >> 4) * 8;
    unsigned short* dst = P + ((nt * 4 + ks) * 64 + lane) * 8;
#pragma unroll
    for (int j = 0; j < 8; ++j)
        dst[j] = f2b_rne(W[(kbase + j) * CH + n]);
}

// ---------------- gather v2: one wave/node; dwordx4 loads cover 4 neighbor rows ----------
__global__ __launch_bounds__(256) void gather_agg_v2(const unsigned short* __restrict__ feat,
                                                     const int* __restrict__ adj,
                                                     const int* __restrict__ cnt,
                                                     unsigned short* __restrict__ agg) {
    int node = blockIdx.x * 4 + (threadIdx.x >> 6);
    int lane = threadIdx.x & 63;
    if (node >= N_NODES) return;
    int grp = lane >> 4, l16 = lane & 15;
    int deg = cnt[node]; if (deg > CAP) deg = CAP;
    int nb = (lane < deg) ? adj[(node << 6) + lane] : 0;

    float acc[8];
#pragma unroll
    for (int c = 0; c < 8; ++c) acc[c] = 0.f;

    const uint4* f4 = reinterpret_cast<const uint4*>(feat);  // row = ROW4 uint4
    const uint4 z4 = make_uint4(0, 0, 0, 0);
    for (int j = 0; j < deg; j += 8) {
        int ja = j + grp, jb = ja + 4;
        int sa = __shfl(nb, ja, 64);
        int sb = __shfl(nb, jb, 64);
        uint4 va = (ja < deg) ? f4[sa * ROW4 + l16] : z4;
        uint4 vb = (jb < deg) ? f4[sb * ROW4 + l16] : z4;
        acc2(acc[0], acc[1], va.x); acc2(acc[2], acc[3], va.y);
        acc2(acc[4], acc[5], va.z); acc2(acc[6], acc[7], va.w);
        acc2(acc[0], acc[1], vb.x); acc2(acc[2], acc[3], vb.y);
        acc2(acc[4], acc[5], vb.z); acc2(acc[6], acc[7], vb.w);
    }
    // reduce the 4 neighbor-groups (lane bits 4,5)
#pragma unroll
    for (int c = 0; c < 8; ++c) {
        acc[c] += __shfl_xor(acc[c], 16, 64);
        acc[c] += __shfl_xor(acc[c], 32, 64);
    }
    if (grp == 0) {
        uint4 sv = f4[node * ROW4 + l16];   // self term
        acc2(acc[0], acc[1], sv.x); acc2(acc[2], acc[3], sv.y);
        acc2(acc[4], acc[5], sv.z); acc2(acc[6], acc[7], sv.w);
        uint4 o;
        o.x = (unsigned)f2b_rne(acc[0]) | ((unsigned)f2b_rne(acc[1]) << 16);
        o.y = (unsigned)f2b_rne(acc[2]) | ((unsigned)f2b_rne(acc[3]) << 16);
        o.z = (unsigned)f2b_rne(acc[4]) | ((unsigned)f2b_rne(acc[5]) << 16);
        o.w = (unsigned)f2b_rne(acc[6]) | ((unsigned)f2b_rne(acc[7]) << 16);
        reinterpret_cast<uint4*>(agg)[node * ROW4 + l16] = o;
    }
}

// ---------------- bf16 MFMA GEMM: C = relu(A[M,128] @ W[128,128] + b), bf16 out ----------
__global__ __launch_bounds__(256) void gemm_mfma_bias_relu(const unsigned short* __restrict__ A,
                                                           const unsigned short* __restrict__ Bp,
                                                           const float* __restrict__ bias,
                                                           unsigned short* __restrict__ Cout,
                                                           int M) {
    __shared__ unsigned short As[64 * 136];
    const int row0 = blockIdx.x * 64;
    const int tid = threadIdx.x;

    {
        int r = tid & 63, seg = tid >> 6;
        int row = row0 + r;
        uint4 z = make_uint4(0, 0, 0, 0);
        const uint4* src = reinterpret_cast<const uint4*>(A + (long long)row * CH + seg * 32);
        uint4* dst = reinterpret_cast<uint4*>(&As[r * 136 + seg * 32]);
#pragma unroll
        for (int i = 0; i < 4; ++i)
            dst[i] = (row < M) ? src[i] : z;
    }
    __syncthreads();

    const int wave = tid >> 6;
    const int lane = tid & 63;
    const int quad = lane >> 4;
    const int l15 = lane & 15;

    f32x4 acc[8];
#pragma unroll
    for (int nt = 0; nt < 8; ++nt) acc[nt] = (f32x4){0.f, 0.f, 0.f, 0.f};

#pragma unroll
    for (int ks = 0; ks < 4; ++ks) {
        bf16x8s afrag = *reinterpret_cast<const bf16x8s*>(
            &As[(wave * 16 + l15) * 136 + ks * 32 + quad * 8]);
#pragma unroll
        for (int nt = 0; nt < 8; ++nt) {
            bf16x8s bfrag = *reinterpret_cast<const bf16x8s*>(
                Bp + ((nt * 4 + ks) * 64 + lane) * 8);
            acc[nt] = __builtin_amdgcn_mfma_f32_16x16x32_bf16(afrag, bfrag, acc[nt], 0, 0, 0);
        }
    }

#pragma unroll
    for (int nt = 0; nt < 8; ++nt) {
        int col = nt * 16 + l15;
        float bv = bias[col];
#pragma unroll
        for (int r = 0; r < 4; ++r) {
            int row = row0 + wave * 16 + quad * 4 + r;
            if (row < M) {
                float v = fmaxf(acc[nt][r] + bv, 0.f);
                Cout[(long long)row * CH + col] = f2b_rne(v);
            }
        }
    }
}

// ---------------- final: logits = H[M,128](bf16) @ W2b[128,40] + b; log_softmax ----------
__global__ __launch_bounds__(256) void gemv40_logsoftmax(const unsigned int* __restrict__ H,
                                                         const float* __restrict__ W,
                                                         const float* __restrict__ bias,
                                                         float* __restrict__ out, int M) {
    __shared__ float hrow[4][128];
    const int wave = threadIdx.x >> 6;
    const int lane = threadIdx.x & 63;
    const int row = blockIdx.x * 4 + wave;
    if (row >= M) return;

    unsigned int v = H[row * 64 + lane];
    hrow[wave][lane * 2] = b2f((unsigned short)(v & 0xFFFF));
    hrow[wave][lane * 2 + 1] = b2f((unsigned short)(v >> 16));

    float acc = 0.f;
    if (lane < OUTC) {
#pragma unroll 8
        for (int k = 0; k < 128; ++k)
            acc += hrow[wave][k] * W[k * OUTC + lane];
        acc += bias[lane];
    }

    float m = (lane < OUTC) ? acc : -1e30f;
#pragma unroll
    for (int off = 32; off; off >>= 1) m = fmaxf(m, __shfl_xor(m, off, 64));
    float e = (lane < OUTC) ? __expf(acc - m) : 0.f;
    float ssum = e;
#pragma unroll
    for (int off = 32; off; off >>= 1) ssum += __shfl_xor(ssum, off, 64);
    if (lane < OUTC)
        out[(long long)row * OUTC + lane] = acc - m - __logf(ssum);
}

extern "C" void kernel_launch(void* const* d_in, const int* in_sizes, int n_in,
                              void* d_out, int out_size, void* d_ws, size_t ws_size,
                              hipStream_t stream) {
    const float* x   = (const float*)d_in[0];
    const int* eidx  = (const int*)d_in[1];
    const int* esrc  = eidx;
    const int* edst  = eidx + N_EDGES;
    const float* W1a = (const float*)d_in[2];
    const float* b1a = (const float*)d_in[3];
    const float* W1b = (const float*)d_in[4];
    const float* b1b = (const float*)d_in[5];
    const float* W2a = (const float*)d_in[6];
    const float* b2a = (const float*)d_in[7];
    const float* W2b = (const float*)d_in[8];
    const float* b2b = (const float*)d_in[9];
    float* out = (float*)d_out;

    const size_t fe = (size_t)N_NODES * CH;
    unsigned short* xb = (unsigned short*)d_ws;           // 25.6 MB
    unsigned short* b0 = xb + fe;
    unsigned short* b1 = b0 + fe;
    unsigned short* b2 = b1 + fe;
    int* adj     = (int*)(b2 + fe);                       // 25.6 MB
    int* cnt     = adj + (size_t)N_NODES * CAP;           // 400 KB
    int* gcursor = cnt + N_NODES;                         // 98 ints
    uint2* bins  = (uint2*)(gcursor + NBKT + 1);          // 14.45 MB (8B-aligned)
    unsigned short* P1 = (unsigned short*)(bins + (size_t)NBKT * BKT_CAP);
    unsigned short* P2 = P1 + 16384;
    unsigned short* P3 = P2 + 16384;
    // total ~143 MB < 153.6 MB proven available

    const int conv_grid  = (int)((fe / 8 + 255) / 256);
    const int bin_grid   = (N_EDGES + P1_EDGES - 1) / P1_EDGES;   // 391
    const int gath_grid  = (N_NODES + 3) / 4;
    const int gemm_grid  = (N_NODES + 63) / 64;
    const int gemv_grid  = (N_NODES + 3) / 4;

    conv_f32_bf16<<<conv_grid, 256, 0, stream>>>((const float4*)x, (ushort4*)xb, (int)(fe / 8));
    zero_ints<<<1, 256, 0, stream>>>(gcursor, NBKT);
    bin_edges<<<bin_grid, 256, 0, stream>>>(esrc, edst, gcursor, bins);
    build_from_bins<<<NBKT, 256, 0, stream>>>(bins, gcursor, adj, cnt);
    pack_w3<<<24, 256, 0, stream>>>(W1a, W1b, W2a, P1, P2, P3);

    // ---- layer 1 ----
    gather_agg_v2<<<gath_grid, 256, 0, stream>>>(xb, adj, cnt, b0);
    gemm_mfma_bias_relu<<<gemm_grid, 256, 0, stream>>>(b0, P1, b1a, b1, N_NODES);
    gemm_mfma_bias_relu<<<gemm_grid, 256, 0, stream>>>(b1, P2, b1b, b2, N_NODES);

    // ---- layer 2 ----
    gather_agg_v2<<<gath_grid, 256, 0, stream>>>(b2, adj, cnt, b0);
    gemm_mfma_bias_relu<<<gemm_grid, 256, 0, stream>>>(b0, P3, b2a, b1, N_NODES);
    gemv40_logsoftmax<<<gemv_grid, 256, 0, stream>>>((const unsigned int*)b1, W2b, b2b,
                                                     out, N_NODES);
}

// Round 6
// 445.698 us; speedup vs baseline: 1.1812x; 1.1812x over previous
//
#include <hip/hip_runtime.h>

#define N_NODES 100000
#define N_EDGES 1600000
#define CH 128
#define OUTC 40
#define CAP 64        // max in-degree; Poisson(16) => P(>=64) ~ 1e-20
#define NBKT 98       // buckets by dst>>10 (1024 nodes each)
#define BKT_CAP 18432 // mean 16384, sigma ~127 -> 16-sigma headroom
#define P1_EDGES 4096 // edges binned per block
#define ROW4 16       // uint4 per feature row: 128 bf16 = 256 B = 16 * 16 B

typedef __attribute__((ext_vector_type(8))) short bf16x8s;
typedef __attribute__((ext_vector_type(4))) float f32x4;

__device__ __forceinline__ unsigned short f2b_rne(float f) {
    union { float f; unsigned int u; } c; c.f = f;
    unsigned int r = (c.u + 0x7FFF + ((c.u >> 16) & 1)) >> 16;
    return (unsigned short)r;
}
__device__ __forceinline__ float b2f(unsigned short b) {
    union { float f; unsigned int u; } c; c.u = ((unsigned int)b) << 16;
    return c.f;
}
__device__ __forceinline__ void acc2(float& a0, float& a1, unsigned int v) {
    a0 += b2f((unsigned short)(v & 0xFFFF));
    a1 += b2f((unsigned short)(v >> 16));
}

// ---------------- fp32 -> bf16 convert ----------------
__global__ __launch_bounds__(256) void conv_f32_bf16(const float4* __restrict__ in,
                                                     ushort4* __restrict__ out, int n8) {
    int i = blockIdx.x * 256 + threadIdx.x;
    if (i >= n8) return;
    float4 a = in[i * 2], b = in[i * 2 + 1];
    ushort4 o0, o1;
    o0.x = f2b_rne(a.x); o0.y = f2b_rne(a.y); o0.z = f2b_rne(a.z); o0.w = f2b_rne(a.w);
    o1.x = f2b_rne(b.x); o1.y = f2b_rne(b.y); o1.z = f2b_rne(b.z); o1.w = f2b_rne(b.w);
    out[i * 2] = o0; out[i * 2 + 1] = o1;
}

__global__ __launch_bounds__(256) void zero_ints(int* __restrict__ p, int n) {
    int i = blockIdx.x * 256 + threadIdx.x;
    if (i < n) p[i] = 0;
}

// ---------------- P1: bin edges by destination bucket (coalesced writes) ----------------
__global__ __launch_bounds__(256) void bin_edges(const int* __restrict__ esrc,
                                                 const int* __restrict__ edst,
                                                 int* __restrict__ gcursor,
                                                 uint2* __restrict__ bins) {
    __shared__ uint2 stage[P1_EDGES];      // 32 KB
    __shared__ int lcnt[NBKT];
    __shared__ int lofs[NBKT];             // inclusive scan
    __shared__ int lpos[NBKT];             // running placement cursor
    __shared__ int gbase[NBKT];
    const int tid = threadIdx.x;
    const int e0 = blockIdx.x * P1_EDGES;

    for (int i = tid; i < NBKT; i += 256) lcnt[i] = 0;
    __syncthreads();

    int s[16], d[16];
#pragma unroll
    for (int i = 0; i < 16; ++i) {
        int e = e0 + i * 256 + tid;
        if (e < N_EDGES) { s[i] = esrc[e]; d[i] = edst[e]; }
        else d[i] = -1;
    }
#pragma unroll
    for (int i = 0; i < 16; ++i)
        if (d[i] >= 0) atomicAdd(&lcnt[d[i] >> 10], 1);
    __syncthreads();

    // Kogge-Stone inclusive scan over NBKT entries
    if (tid < NBKT) lofs[tid] = lcnt[tid];
    __syncthreads();
    for (int dd = 1; dd < NBKT; dd <<= 1) {
        int v = 0;
        if (tid < NBKT && tid >= dd) v = lofs[tid - dd];
        __syncthreads();
        if (tid < NBKT) lofs[tid] += v;
        __syncthreads();
    }
    if (tid < NBKT) {
        lpos[tid] = lofs[tid] - lcnt[tid];                 // exclusive base
        gbase[tid] = atomicAdd(&gcursor[tid], lcnt[tid]);  // claim global range
    }
    __syncthreads();

    // place records into LDS, grouped by bucket
#pragma unroll
    for (int i = 0; i < 16; ++i) {
        if (d[i] >= 0) {
            int b = d[i] >> 10;
            int slot = atomicAdd(&lpos[b], 1);
            stage[slot] = make_uint2((unsigned)s[i], (unsigned)d[i]);
        }
    }
    __syncthreads();

    // coalesced copy-out: consecutive r in a bucket -> consecutive global slots
    int total = lofs[NBKT - 1];
    for (int r = tid; r < total; r += 256) {
        uint2 rec = stage[r];
        int b = (int)(rec.y >> 10);
        int excl = lofs[b] - lcnt[b];
        int pos = gbase[b] + (r - excl);
        if (pos < BKT_CAP) bins[(size_t)b * BKT_CAP + pos] = rec;
    }
}

// ---------------- P2: build adj from bins (one block per bucket; single-XCD writes) ----------
__global__ __launch_bounds__(256) void build_from_bins(const uint2* __restrict__ bins,
                                                       const int* __restrict__ gcursor,
                                                       int* __restrict__ adj,
                                                       int* __restrict__ cnt) {
    __shared__ int lc[1024];
    const int b = blockIdx.x;
    const int tid = threadIdx.x;
    const int base = b << 10;
    for (int i = tid; i < 1024; i += 256) lc[i] = 0;
    __syncthreads();
    int n = gcursor[b]; if (n > BKT_CAP) n = BKT_CAP;
    const uint2* myb = bins + (size_t)b * BKT_CAP;
    for (int i = tid; i < n; i += 256) {
        uint2 r = myb[i];
        int local = (int)r.y - base;
        int slot = atomicAdd(&lc[local], 1);
        if (slot < CAP) adj[((int)r.y << 6) + slot] = (int)r.x;
    }
    __syncthreads();
    for (int i = tid; i < 1024; i += 256) {
        int node = base + i;
        if (node < N_NODES) cnt[node] = lc[i];
    }
}

// ---------------- pack hidden-layer weights into MFMA B-frag order ----------------
__global__ __launch_bounds__(256) void pack_w3(const float* __restrict__ W0,
                                               const float* __restrict__ W1,
                                               const float* __restrict__ W2,
                                               unsigned short* __restrict__ P0,
                                               unsigned short* __restrict__ P1,
                                               unsigned short* __restrict__ P2) {
    int t = blockIdx.x * 256 + threadIdx.x;
    if (t >= 3 * 2048) return;
    int which = t >> 11;
    int rem = t & 2047;
    int lane = rem & 63;
    int ks = (rem >> 6) & 3;
    int nt = rem >> 8;
    const float* W = which == 0 ? W0 : (which == 1 ? W1 : W2);
    unsigned short* P = which == 0 ? P0 : (which == 1 ? P1 : P2);
    int n = nt * 16 + (lane & 15);
    int kbase = ks * 32 + (lane >> 4) * 8;
    unsigned short* dst = P + ((nt * 4 + ks) * 64 + lane) * 8;
#pragma unroll
    for (int j = 0; j < 8; ++j)
        dst[j] = f2b_rne(W[(kbase + j) * CH + n]);
}

// ---------------- pack output weights W[128,40] -> 48 cols (40..47 zero) ----------------
__global__ __launch_bounds__(256) void pack_wout(const float* __restrict__ W,
                                                 unsigned short* __restrict__ P) {
    int t = blockIdx.x * 256 + threadIdx.x;   // 768 threads
    if (t >= 768) return;
    int nt = t >> 8, rem = t & 255;
    int ks = rem >> 6, lane = rem & 63;
    int n = nt * 16 + (lane & 15);
    int kbase = ks * 32 + (lane >> 4) * 8;
    unsigned short* dst = P + ((nt * 4 + ks) * 64 + lane) * 8;
#pragma unroll
    for (int j = 0; j < 8; ++j)
        dst[j] = (n < OUTC) ? f2b_rne(W[(kbase + j) * OUTC + n]) : (unsigned short)0;
}

// ---------------- gather v2: one wave/node; dwordx4 loads cover 4 neighbor rows ----------
__global__ __launch_bounds__(256) void gather_agg_v2(const unsigned short* __restrict__ feat,
                                                     const int* __restrict__ adj,
                                                     const int* __restrict__ cnt,
                                                     unsigned short* __restrict__ agg) {
    int node = blockIdx.x * 4 + (threadIdx.x >> 6);
    int lane = threadIdx.x & 63;
    if (node >= N_NODES) return;
    int grp = lane >> 4, l16 = lane & 15;
    int deg = cnt[node]; if (deg > CAP) deg = CAP;
    int nb = (lane < deg) ? adj[(node << 6) + lane] : 0;

    float acc[8];
#pragma unroll
    for (int c = 0; c < 8; ++c) acc[c] = 0.f;

    const uint4* f4 = reinterpret_cast<const uint4*>(feat);  // row = ROW4 uint4
    const uint4 z4 = make_uint4(0, 0, 0, 0);
    for (int j = 0; j < deg; j += 8) {
        int ja = j + grp, jb = ja + 4;
        int sa = __shfl(nb, ja, 64);
        int sb = __shfl(nb, jb, 64);
        uint4 va = (ja < deg) ? f4[sa * ROW4 + l16] : z4;
        uint4 vb = (jb < deg) ? f4[sb * ROW4 + l16] : z4;
        acc2(acc[0], acc[1], va.x); acc2(acc[2], acc[3], va.y);
        acc2(acc[4], acc[5], va.z); acc2(acc[6], acc[7], va.w);
        acc2(acc[0], acc[1], vb.x); acc2(acc[2], acc[3], vb.y);
        acc2(acc[4], acc[5], vb.z); acc2(acc[6], acc[7], vb.w);
    }
    // reduce the 4 neighbor-groups (lane bits 4,5)
#pragma unroll
    for (int c = 0; c < 8; ++c) {
        acc[c] += __shfl_xor(acc[c], 16, 64);
        acc[c] += __shfl_xor(acc[c], 32, 64);
    }
    if (grp == 0) {
        uint4 sv = f4[node * ROW4 + l16];   // self term
        acc2(acc[0], acc[1], sv.x); acc2(acc[2], acc[3], sv.y);
        acc2(acc[4], acc[5], sv.z); acc2(acc[6], acc[7], sv.w);
        uint4 o;
        o.x = (unsigned)f2b_rne(acc[0]) | ((unsigned)f2b_rne(acc[1]) << 16);
        o.y = (unsigned)f2b_rne(acc[2]) | ((unsigned)f2b_rne(acc[3]) << 16);
        o.z = (unsigned)f2b_rne(acc[4]) | ((unsigned)f2b_rne(acc[5]) << 16);
        o.w = (unsigned)f2b_rne(acc[6]) | ((unsigned)f2b_rne(acc[7]) << 16);
        reinterpret_cast<uint4*>(agg)[node * ROW4 + l16] = o;
    }
}

// ---------------- bf16 MFMA GEMM: C = relu(A[M,128] @ W[128,128] + b), bf16 out ----------
__global__ __launch_bounds__(256) void gemm_mfma_bias_relu(const unsigned short* __restrict__ A,
                                                           const unsigned short* __restrict__ Bp,
                                                           const float* __restrict__ bias,
                                                           unsigned short* __restrict__ Cout,
                                                           int M) {
    __shared__ unsigned short As[64 * 136];
    const int row0 = blockIdx.x * 64;
    const int tid = threadIdx.x;

    {
        int r = tid & 63, seg = tid >> 6;
        int row = row0 + r;
        uint4 z = make_uint4(0, 0, 0, 0);
        const uint4* src = reinterpret_cast<const uint4*>(A + (long long)row * CH + seg * 32);
        uint4* dst = reinterpret_cast<uint4*>(&As[r * 136 + seg * 32]);
#pragma unroll
        for (int i = 0; i < 4; ++i)
            dst[i] = (row < M) ? src[i] : z;
    }
    __syncthreads();

    const int wave = tid >> 6;
    const int lane = tid & 63;
    const int quad = lane >> 4;
    const int l15 = lane & 15;

    f32x4 acc[8];
#pragma unroll
    for (int nt = 0; nt < 8; ++nt) acc[nt] = (f32x4){0.f, 0.f, 0.f, 0.f};

#pragma unroll
    for (int ks = 0; ks < 4; ++ks) {
        bf16x8s afrag = *reinterpret_cast<const bf16x8s*>(
            &As[(wave * 16 + l15) * 136 + ks * 32 + quad * 8]);
#pragma unroll
        for (int nt = 0; nt < 8; ++nt) {
            bf16x8s bfrag = *reinterpret_cast<const bf16x8s*>(
                Bp + ((nt * 4 + ks) * 64 + lane) * 8);
            acc[nt] = __builtin_amdgcn_mfma_f32_16x16x32_bf16(afrag, bfrag, acc[nt], 0, 0, 0);
        }
    }

#pragma unroll
    for (int nt = 0; nt < 8; ++nt) {
        int col = nt * 16 + l15;
        float bv = bias[col];
#pragma unroll
        for (int r = 0; r < 4; ++r) {
            int row = row0 + wave * 16 + quad * 4 + r;
            if (row < M) {
                float v = fmaxf(acc[nt][r] + bv, 0.f);
                Cout[(long long)row * CH + col] = f2b_rne(v);
            }
        }
    }
}

// ---------------- final: logits = H @ W2b + b (MFMA, 48-col pad); log_softmax ----------
// Wave = 16 rows. A-frag straight from global. Row r of C lives across the 16
// lanes of quad (col = l15) x 3 nt-regs -> butterfly shfl_xor{1,2,4,8} reduces it.
__global__ __launch_bounds__(256) void mfma40_logsoftmax(const unsigned short* __restrict__ H,
                                                         const unsigned short* __restrict__ Pb,
                                                         const float* __restrict__ bias,
                                                         float* __restrict__ out, int M) {
    const int tid = threadIdx.x;
    const int wave = tid >> 6;
    const int lane = tid & 63;
    const int quad = lane >> 4;
    const int l15 = lane & 15;
    int rowA = blockIdx.x * 64 + wave * 16 + l15;
    if (rowA >= M) rowA = M - 1;     // clamp: overflow rows never written
    const long long rbase = (long long)rowA * CH;

    f32x4 acc[3];
#pragma unroll
    for (int nt = 0; nt < 3; ++nt) acc[nt] = (f32x4){0.f, 0.f, 0.f, 0.f};

#pragma unroll
    for (int ks = 0; ks < 4; ++ks) {
        bf16x8s a = *reinterpret_cast<const bf16x8s*>(H + rbase + ks * 32 + quad * 8);
#pragma unroll
        for (int nt = 0; nt < 3; ++nt) {
            bf16x8s b = *reinterpret_cast<const bf16x8s*>(Pb + ((nt * 4 + ks) * 64 + lane) * 8);
            acc[nt] = __builtin_amdgcn_mfma_f32_16x16x32_bf16(a, b, acc[nt], 0, 0, 0);
        }
    }

    const float b0v = bias[l15];
    const float b1v = bias[16 + l15];
    const float b2v = (l15 < 8) ? bias[32 + l15] : 0.f;

#pragma unroll
    for (int r = 0; r < 4; ++r) {
        int row = blockIdx.x * 64 + wave * 16 + quad * 4 + r;
        float v0 = acc[0][r] + b0v;
        float v1 = acc[1][r] + b1v;
        float v2 = (l15 < 8) ? (acc[2][r] + b2v) : -1e30f;
        float m = fmaxf(fmaxf(v0, v1), v2);
#pragma unroll
        for (int off = 1; off < 16; off <<= 1) m = fmaxf(m, __shfl_xor(m, off, 64));
        float s = __expf(v0 - m) + __expf(v1 - m) + ((l15 < 8) ? __expf(v2 - m) : 0.f);
#pragma unroll
        for (int off = 1; off < 16; off <<= 1) s += __shfl_xor(s, off, 64);
        float lg = m + __logf(s);
        if (row < M) {
            float* orow = out + (long long)row * OUTC;
            orow[l15] = v0 - lg;
            orow[16 + l15] = v1 - lg;
            if (l15 < 8) orow[32 + l15] = v2 - lg;
        }
    }
}

extern "C" void kernel_launch(void* const* d_in, const int* in_sizes, int n_in,
                              void* d_out, int out_size, void* d_ws, size_t ws_size,
                              hipStream_t stream) {
    const float* x   = (const float*)d_in[0];
    const int* eidx  = (const int*)d_in[1];
    const int* esrc  = eidx;
    const int* edst  = eidx + N_EDGES;
    const float* W1a = (const float*)d_in[2];
    const float* b1a = (const float*)d_in[3];
    const float* W1b = (const float*)d_in[4];
    const float* b1b = (const float*)d_in[5];
    const float* W2a = (const float*)d_in[6];
    const float* b2a = (const float*)d_in[7];
    const float* W2b = (const float*)d_in[8];
    const float* b2b = (const float*)d_in[9];
    float* out = (float*)d_out;

    const size_t fe = (size_t)N_NODES * CH;
    unsigned short* xb = (unsigned short*)d_ws;           // 25.6 MB
    unsigned short* b0 = xb + fe;
    unsigned short* b1 = b0 + fe;
    unsigned short* b2 = b1 + fe;
    int* adj     = (int*)(b2 + fe);                       // 25.6 MB
    int* cnt     = adj + (size_t)N_NODES * CAP;           // 400 KB
    int* gcursor = cnt + N_NODES;                         // 98 ints
    uint2* bins  = (uint2*)(gcursor + NBKT + 1);          // 14.45 MB (8B-aligned)
    unsigned short* P1 = (unsigned short*)(bins + (size_t)NBKT * BKT_CAP);
    unsigned short* P2 = P1 + 16384;
    unsigned short* P3 = P2 + 16384;
    unsigned short* Pb = P3 + 16384;                      // 6144 bf16 (48-col pad)
    // total ~143 MB < 153.6 MB proven available

    const int conv_grid  = (int)((fe / 8 + 255) / 256);
    const int bin_grid   = (N_EDGES + P1_EDGES - 1) / P1_EDGES;   // 391
    const int gath_grid  = (N_NODES + 3) / 4;
    const int gemm_grid  = (N_NODES + 63) / 64;
    const int fin_grid   = (N_NODES + 63) / 64;

    conv_f32_bf16<<<conv_grid, 256, 0, stream>>>((const float4*)x, (ushort4*)xb, (int)(fe / 8));
    zero_ints<<<1, 256, 0, stream>>>(gcursor, NBKT);
    bin_edges<<<bin_grid, 256, 0, stream>>>(esrc, edst, gcursor, bins);
    build_from_bins<<<NBKT, 256, 0, stream>>>(bins, gcursor, adj, cnt);
    pack_w3<<<24, 256, 0, stream>>>(W1a, W1b, W2a, P1, P2, P3);
    pack_wout<<<3, 256, 0, stream>>>(W2b, Pb);

    // ---- layer 1 ----
    gather_agg_v2<<<gath_grid, 256, 0, stream>>>(xb, adj, cnt, b0);
    gemm_mfma_bias_relu<<<gemm_grid, 256, 0, stream>>>(b0, P1, b1a, b1, N_NODES);
    gemm_mfma_bias_relu<<<gemm_grid, 256, 0, stream>>>(b1, P2, b1b, b2, N_NODES);

    // ---- layer 2 ----
    gather_agg_v2<<<gath_grid, 256, 0, stream>>>(b2, adj, cnt, b0);
    gemm_mfma_bias_relu<<<gemm_grid, 256, 0, stream>>>(b0, P3, b2a, b1, N_NODES);
    mfma40_logsoftmax<<<fin_grid, 256, 0, stream>>>(b1, Pb, b2b, out, N_NODES);
}